// Round 1
// baseline (119.551 us; speedup 1.0000x reference)
//
#include <hip/hip_runtime.h>
#include <hip/hip_bf16.h>

// Encoding layer (Deep-TEN). B=16, D=128, K=32, N=H*W=4096.
// E[b,k,d] = sum_n A[b,n,k]*(X[b,n,d]-C[k,d]),  A = softmax_k(scale[k]*||X-C_k||^2)
// x layout: (B, D, H, W) -> X[b,n,d] = x[b*D*N + d*N + n]
//
// One fused kernel per (b, n-tile of 128):
//   pass1: xc[n,k] = X.C^T (x coalesced from global, C^T broadcast from LDS)
//   softmax: fully per-thread in-register over K=32
//   pass2: E partial = A^T X - Asum*C, atomicAdd into zeroed d_out

#define D_    128
#define K_    32
#define NPB   128          // n per block
#define NTOT  4096         // H*W
#define ALD   36           // LDS row stride for xc/A (pad: 36 floats, 16B-aligned rows)

__global__ __launch_bounds__(256) void enc_kernel(
    const float* __restrict__ x,
    const float* __restrict__ cw,
    const float* __restrict__ scale,
    float* __restrict__ out)
{
  __shared__ __align__(16) float sC[D_ * K_];   // C transposed: [d][k], 16 KB
  __shared__ __align__(16) float sA[NPB * ALD]; // xc then A: [n][k], 18.4 KB
  __shared__ float ssc[K_];
  __shared__ float sc2[K_];
  __shared__ float sasum[K_];

  const int t  = threadIdx.x;
  const int b  = blockIdx.x >> 5;
  const int n0 = (blockIdx.x & 31) * NPB;

  // ---- phase 0: stage C^T, scale; zero block asum ----
  #pragma unroll
  for (int i = 0; i < 16; ++i) {
    int idx = i * 256 + t;                       // 4096 = K*D elements
    sC[(idx & 127) * K_ + (idx >> 7)] = cw[idx]; // [d][k] = C[k][d]
  }
  if (t < K_) { ssc[t] = scale[t]; sasum[t] = 0.0f; }
  __syncthreads();
  if (t < K_) {                                  // c2[k] = ||C_k||^2
    float s = 0.0f;
    #pragma unroll 8
    for (int d = 0; d < D_; ++d) { float c = sC[d * K_ + t]; s = fmaf(c, c, s); }
    sc2[t] = s;
  }

  // ---- pass 1: xc[n][k] = sum_d X[n,d]*C[k,d]; also x2[n] ----
  const int n  = t & (NPB - 1);
  const int kh = t >> 7;                         // 0/1: which 16-k half
  const float* xp = x + (size_t)b * D_ * NTOT + n0 + n;
  float acc[16];
  #pragma unroll
  for (int i = 0; i < 16; ++i) acc[i] = 0.0f;
  float x2 = 0.0f;
  const float4* sC4 = reinterpret_cast<const float4*>(sC);
  #pragma unroll 4
  for (int d = 0; d < D_; ++d) {
    float xv = xp[(size_t)d * NTOT];             // coalesced: lanes vary n
    x2 = fmaf(xv, xv, x2);
    float4 c0 = sC4[d * 8 + kh * 4 + 0];         // LDS broadcast (uniform addr)
    float4 c1 = sC4[d * 8 + kh * 4 + 1];
    float4 c2 = sC4[d * 8 + kh * 4 + 2];
    float4 c3 = sC4[d * 8 + kh * 4 + 3];
    acc[ 0] = fmaf(xv, c0.x, acc[ 0]);
    acc[ 1] = fmaf(xv, c0.y, acc[ 1]);
    acc[ 2] = fmaf(xv, c0.z, acc[ 2]);
    acc[ 3] = fmaf(xv, c0.w, acc[ 3]);
    acc[ 4] = fmaf(xv, c1.x, acc[ 4]);
    acc[ 5] = fmaf(xv, c1.y, acc[ 5]);
    acc[ 6] = fmaf(xv, c1.z, acc[ 6]);
    acc[ 7] = fmaf(xv, c1.w, acc[ 7]);
    acc[ 8] = fmaf(xv, c2.x, acc[ 8]);
    acc[ 9] = fmaf(xv, c2.y, acc[ 9]);
    acc[10] = fmaf(xv, c2.z, acc[10]);
    acc[11] = fmaf(xv, c2.w, acc[11]);
    acc[12] = fmaf(xv, c3.x, acc[12]);
    acc[13] = fmaf(xv, c3.y, acc[13]);
    acc[14] = fmaf(xv, c3.z, acc[14]);
    acc[15] = fmaf(xv, c3.w, acc[15]);
  }
  {
    float4* w4 = reinterpret_cast<float4*>(&sA[n * ALD + kh * 16]);
    w4[0] = make_float4(acc[ 0], acc[ 1], acc[ 2], acc[ 3]);
    w4[1] = make_float4(acc[ 4], acc[ 5], acc[ 6], acc[ 7]);
    w4[2] = make_float4(acc[ 8], acc[ 9], acc[10], acc[11]);
    w4[3] = make_float4(acc[12], acc[13], acc[14], acc[15]);
  }
  __syncthreads();

  // ---- phase 2: softmax over K=32, per-thread in-register (t<128, n=t) ----
  if (t < NPB) {
    float a[32];
    const float4* r4 = reinterpret_cast<const float4*>(&sA[t * ALD]);
    #pragma unroll
    for (int q = 0; q < 8; ++q) {
      float4 v = r4[q];
      a[4*q+0] = v.x; a[4*q+1] = v.y; a[4*q+2] = v.z; a[4*q+3] = v.w;
    }
    float m = -3.4e38f;
    #pragma unroll
    for (int k = 0; k < K_; ++k) {
      a[k] = ssc[k] * (x2 - 2.0f * a[k] + sc2[k]);   // SL (x2 from pass1: kh==0 thread)
      m = fmaxf(m, a[k]);
    }
    float s = 0.0f;
    #pragma unroll
    for (int k = 0; k < K_; ++k) { a[k] = __expf(a[k] - m); s += a[k]; }
    float inv = 1.0f / s;
    #pragma unroll
    for (int k = 0; k < K_; ++k) a[k] *= inv;
    // block asum[k]: wave-reduce (2 waves active), then LDS atomic
    #pragma unroll
    for (int k = 0; k < K_; ++k) {
      float v = a[k];
      v += __shfl_xor(v, 1);
      v += __shfl_xor(v, 2);
      v += __shfl_xor(v, 4);
      v += __shfl_xor(v, 8);
      v += __shfl_xor(v, 16);
      v += __shfl_xor(v, 32);
      if ((t & 63) == 0) atomicAdd(&sasum[k], v);
    }
    float4* w4 = reinterpret_cast<float4*>(&sA[t * ALD]);   // overwrite own row with A
    #pragma unroll
    for (int q = 0; q < 8; ++q)
      w4[q] = make_float4(a[4*q+0], a[4*q+1], a[4*q+2], a[4*q+3]);
  }
  __syncthreads();

  // ---- pass 2: E_p[k][d] = sum_n A[n,k]*X[n,d] - asum[k]*C[k,d] ----
  const int dd = t & 63;
  const int kq = t >> 6;           // 0..3 (wave-uniform)
  const int k0 = kq * 8;
  const int d0 = dd * 2;
  float acc2[16];
  #pragma unroll
  for (int j = 0; j < 8; ++j) {    // fuse -asum*C correction into init
    float as = sasum[k0 + j];
    acc2[j]     = -as * sC[ d0      * K_ + k0 + j];
    acc2[8 + j] = -as * sC[(d0 + 1) * K_ + k0 + j];
  }
  const float* xq0 = x + (size_t)(b * D_ + d0) * NTOT + n0;
  const float* xq1 = xq0 + NTOT;
  #pragma unroll 2
  for (int n4 = 0; n4 < NPB / 4; ++n4) {
    float4 xr0 = *reinterpret_cast<const float4*>(xq0 + 4 * n4);  // own d-row, L1/L2
    float4 xr1 = *reinterpret_cast<const float4*>(xq1 + 4 * n4);
    float xs0[4] = {xr0.x, xr0.y, xr0.z, xr0.w};
    float xs1[4] = {xr1.x, xr1.y, xr1.z, xr1.w};
    #pragma unroll
    for (int nn = 0; nn < 4; ++nn) {
      const float4* a4 = reinterpret_cast<const float4*>(&sA[(4 * n4 + nn) * ALD + k0]);
      float4 a0 = a4[0], a1 = a4[1];               // LDS broadcast (wave-uniform addr)
      float v0 = xs0[nn], v1 = xs1[nn];
      acc2[ 0] = fmaf(a0.x, v0, acc2[ 0]);
      acc2[ 1] = fmaf(a0.y, v0, acc2[ 1]);
      acc2[ 2] = fmaf(a0.z, v0, acc2[ 2]);
      acc2[ 3] = fmaf(a0.w, v0, acc2[ 3]);
      acc2[ 4] = fmaf(a1.x, v0, acc2[ 4]);
      acc2[ 5] = fmaf(a1.y, v0, acc2[ 5]);
      acc2[ 6] = fmaf(a1.z, v0, acc2[ 6]);
      acc2[ 7] = fmaf(a1.w, v0, acc2[ 7]);
      acc2[ 8] = fmaf(a0.x, v1, acc2[ 8]);
      acc2[ 9] = fmaf(a0.y, v1, acc2[ 9]);
      acc2[10] = fmaf(a0.z, v1, acc2[10]);
      acc2[11] = fmaf(a0.w, v1, acc2[11]);
      acc2[12] = fmaf(a1.x, v1, acc2[12]);
      acc2[13] = fmaf(a1.y, v1, acc2[13]);
      acc2[14] = fmaf(a1.z, v1, acc2[14]);
      acc2[15] = fmaf(a1.w, v1, acc2[15]);
    }
  }
  float* op = out + (size_t)b * K_ * D_;
  #pragma unroll
  for (int j = 0; j < 8; ++j) {
    unsafeAtomicAdd(&op[(k0 + j) * D_ + d0    ], acc2[j]);
    unsafeAtomicAdd(&op[(k0 + j) * D_ + d0 + 1], acc2[8 + j]);
  }
}

extern "C" void kernel_launch(void* const* d_in, const int* in_sizes, int n_in,
                              void* d_out, int out_size, void* d_ws, size_t ws_size,
                              hipStream_t stream) {
  const float* x  = (const float*)d_in[0];
  const float* cw = (const float*)d_in[1];
  const float* sc = (const float*)d_in[2];
  float* out = (float*)d_out;
  const int B = in_sizes[0] / (D_ * NTOT);   // 16
  hipMemsetAsync(d_out, 0, (size_t)out_size * sizeof(float), stream);
  enc_kernel<<<dim3(B * (NTOT / NPB)), dim3(256), 0, stream>>>(x, cw, sc, out);
}